// Round 7
// baseline (683.392 us; speedup 1.0000x reference)
//
#include <hip/hip_runtime.h>

#define DEG_CAP 96

__device__ __forceinline__ void load4x4(const float* __restrict__ p, float m[4][4]) {
    const float4* q = (const float4*)p;
#pragma unroll
    for (int k = 0; k < 4; ++k) {
        float4 v = q[k];
        m[k][0] = v.x; m[k][1] = v.y; m[k][2] = v.z; m[k][3] = v.w;
    }
}

__device__ __forceinline__ void store4x4(float* __restrict__ p, const float m[4][4]) {
    float4* q = (float4*)p;
#pragma unroll
    for (int k = 0; k < 4; ++k)
        q[k] = make_float4(m[k][0], m[k][1], m[k][2], m[k][3]);
}

// o = a^T * b
__device__ __forceinline__ void mmTa(const float a[4][4], const float b[4][4], float o[4][4]) {
#pragma unroll
    for (int i = 0; i < 4; ++i)
#pragma unroll
        for (int j = 0; j < 4; ++j)
            o[i][j] = a[0][i]*b[0][j] + a[1][i]*b[1][j] + a[2][i]*b[2][j] + a[3][i]*b[3][j];
}

// o = a * b
__device__ __forceinline__ void mm(const float a[4][4], const float b[4][4], float o[4][4]) {
#pragma unroll
    for (int i = 0; i < 4; ++i)
#pragma unroll
        for (int j = 0; j < 4; ++j)
            o[i][j] = a[i][0]*b[0][j] + a[i][1]*b[1][j] + a[i][2]*b[2][j] + a[i][3]*b[3][j];
}

// --- kernel 1 (fused): bucket fill + ALL ei-only index outputs ---------------
// Thread e (< 2E): returning atomic slot-assign + bucket write.
// Thread e (< E): additionally writes tri_ij and tri_ji row/col index blocks
// (256 B of streaming writes) — this BW work overlaps the atomic latency.
__global__ void k_fused1(const int* __restrict__ ei, int* __restrict__ cnt,
                         int* __restrict__ bucket, float* __restrict__ out,
                         size_t Tot, int N, int E) {
    int e = blockIdx.x * blockDim.x + threadIdx.x;
    int twoE = 2 * E;
    if (e >= twoE) return;
    int node = ei[e];
    int slot = atomicAdd(&cnt[(size_t)node * 16], 1);   // 64B-strided counters
    if (slot < DEG_CAP)
        bucket[(size_t)node * DEG_CAP + slot] = e;

    if (e < E) {
        int r = node;                 // ei[e] for e<E is row[e]
        int c = ei[E + e];            // ei[E+e] = col[e]
        float rb = (float)(r * 4);
        float cb = (float)(c * 4);
        // tri_ij rows/cols at element offset 16*N + 16*e
        {
            size_t base = (size_t)16 * N + (size_t)e * 16;
            float4* qr = (float4*)(out + base);
            float4* qc = (float4*)(out + Tot + base);
#pragma unroll
            for (int i = 0; i < 4; ++i) {
                float ri = rb + (float)i;
                qr[i] = make_float4(ri, ri, ri, ri);
                qc[i] = make_float4(cb, cb + 1.0f, cb + 2.0f, cb + 3.0f);
            }
        }
        // tri_ji rows/cols at element offset 16*(N+E) + 16*e
        {
            size_t base = (size_t)16 * (N + (size_t)E) + (size_t)e * 16;
            float4* qr = (float4*)(out + base);
            float4* qc = (float4*)(out + Tot + base);
#pragma unroll
            for (int i = 0; i < 4; ++i) {
                float ci = cb + (float)i;
                qr[i] = make_float4(ci, ci, ci, ci);
                qc[i] = make_float4(rb, rb + 1.0f, rb + 2.0f, rb + 3.0f);
            }
        }
    }
}

// --- kernel 2 (fused): half-wave Gram gather + Jacobi inv-sqrt + diag vals ---
// 32 lanes per node, 2 nodes per wave. After the 5-step butterfly, the sub==0
// lane of each half runs the 4x4 Jacobi, writes Rtab and the clipped diag vals.
__global__ void k_gather_diag(const float* __restrict__ maps, const int* __restrict__ cnt,
                              const int* __restrict__ bucket, float* __restrict__ Rtab,
                              float* __restrict__ out_vals, int N) {
    int tid = blockIdx.x * blockDim.x + threadIdx.x;
    int lane = threadIdx.x & 63;
    int n = (tid >> 6) * 2 + ((lane >> 5) & 1);
    int sub = lane & 31;
    if (n >= N) return;
    int d = cnt[(size_t)n * 16];
    if (d > DEG_CAP) d = DEG_CAP;

    float G[10];
#pragma unroll
    for (int t = 0; t < 10; ++t) G[t] = 0.0f;

#pragma unroll
    for (int rep = 0; rep < 3; ++rep) {
        int slot = sub + rep * 32;
        if (slot < d) {
            int e = bucket[(size_t)n * DEG_CAP + slot];
            float m[4][4];
            load4x4(maps + (size_t)e * 16, m);
            int t = 0;
#pragma unroll
            for (int i = 0; i < 4; ++i)
#pragma unroll
                for (int j = i; j < 4; ++j, ++t)
                    G[t] += m[0][i]*m[0][j] + m[1][i]*m[1][j] + m[2][i]*m[2][j] + m[3][i]*m[3][j];
        }
    }
    // 32-lane butterfly within each half-wave
#pragma unroll
    for (int msk = 1; msk < 32; msk <<= 1) {
#pragma unroll
        for (int t = 0; t < 10; ++t)
            G[t] += __shfl_xor(G[t], msk, 64);
    }

    if (sub != 0) return;

    // --- Jacobi on the reduced Gram (lanes 0 and 32 of each wave) ---
    float D[4][4];
    {
        int t = 0;
#pragma unroll
        for (int i = 0; i < 4; ++i)
#pragma unroll
            for (int j = i; j < 4; ++j, ++t) { D[i][j] = G[t]; D[j][i] = G[t]; }
    }
    float A[4][4], V[4][4];
#pragma unroll
    for (int i = 0; i < 4; ++i)
#pragma unroll
        for (int j = 0; j < 4; ++j) {
            A[i][j] = D[i][j] + (i == j ? 1.0f : 0.0f);
            V[i][j] = (i == j) ? 1.0f : 0.0f;
        }
    const int PP[6] = {0,0,0,1,1,2};
    const int QQ[6] = {1,2,3,2,3,3};
    for (int sweep = 0; sweep < 6; ++sweep) {
        for (int r = 0; r < 6; ++r) {
            int p = PP[r], q = QQ[r];
            float apq = A[p][q];
            if (fabsf(apq) < 1e-12f) continue;
            float tau = (A[q][q] - A[p][p]) / (2.0f * apq);
            float t = copysignf(1.0f, tau) / (fabsf(tau) + sqrtf(1.0f + tau * tau));
            float c = 1.0f / sqrtf(1.0f + t * t);
            float s = t * c;
#pragma unroll
            for (int k = 0; k < 4; ++k) {
                float akp = A[k][p], akq = A[k][q];
                A[k][p] = c * akp - s * akq;
                A[k][q] = s * akp + c * akq;
            }
#pragma unroll
            for (int k = 0; k < 4; ++k) {
                float apk = A[p][k], aqk = A[q][k];
                A[p][k] = c * apk - s * aqk;
                A[q][k] = s * apk + c * aqk;
            }
#pragma unroll
            for (int k = 0; k < 4; ++k) {
                float vkp = V[k][p], vkq = V[k][q];
                V[k][p] = c * vkp - s * vkq;
                V[k][q] = s * vkp + c * vkq;
            }
        }
    }
    float w[4];
#pragma unroll
    for (int k = 0; k < 4; ++k)
        w[k] = 1.0f / sqrtf(fmaxf(A[k][k], 1e-8f));
    float R[4][4];
#pragma unroll
    for (int i = 0; i < 4; ++i)
#pragma unroll
        for (int j = 0; j < 4; ++j)
            R[i][j] = V[i][0]*w[0]*V[j][0] + V[i][1]*w[1]*V[j][1]
                    + V[i][2]*w[2]*V[j][2] + V[i][3]*w[3]*V[j][3];
    store4x4(Rtab + (size_t)n * 16, R);
    float U[4][4], O[4][4];
    mm(R, D, U);
    mm(U, R, O);
#pragma unroll
    for (int i = 0; i < 4; ++i)
#pragma unroll
        for (int j = 0; j < 4; ++j)
            O[i][j] = fminf(fmaxf(O[i][j], -1.0f), 1.0f);
    store4x4(out_vals + (size_t)n * 16, O);
}

// --- kernel 3: per-edge sandwich — VALS ONLY ---------------------------------
__global__ void k_edge_vals(const float* __restrict__ maps, const int* __restrict__ ei,
                            const float* __restrict__ Rtab,
                            float* __restrict__ out_vals, int N, int E) {
    int e = blockIdx.x * blockDim.x + threadIdx.x;
    if (e >= E) return;
    float M1[4][4], M2[4][4];
    load4x4(maps + (size_t)e * 16, M1);
    load4x4(maps + (size_t)(E + e) * 16, M2);
    int r = ei[e];
    int c = ei[2 * E + e];
    float T[4][4];
    mmTa(M1, M2, T);           // T = M1^T * M2
    float Rr[4][4], Rc[4][4];
    load4x4(Rtab + (size_t)r * 16, Rr);
    load4x4(Rtab + (size_t)c * 16, Rc);
    float U[4][4], S[4][4];
    mm(Rr, T, U);
    mm(U, Rc, S);
#pragma unroll
    for (int i = 0; i < 4; ++i)
#pragma unroll
        for (int j = 0; j < 4; ++j)
            S[i][j] = fminf(fmaxf(S[i][j], -1.0f), 1.0f);

    float4* qv1 = (float4*)(out_vals + (size_t)16 * N + (size_t)e * 16);
    float4* qv2 = (float4*)(out_vals + (size_t)16 * (N + (size_t)E) + (size_t)e * 16);
#pragma unroll
    for (int i = 0; i < 4; ++i) {
        qv1[i] = make_float4(-S[i][0], -S[i][1], -S[i][2], -S[i][3]);
        qv2[i] = make_float4(-S[0][i], -S[1][i], -S[2][i], -S[3][i]);
    }
}

// --- kernel 4: diag row/col indices (overwrites the R-table scratch) ---------
__global__ void k_nodeB(float* __restrict__ out, size_t Tot, int N) {
    int n = blockIdx.x * blockDim.x + threadIdx.x;
    if (n >= N) return;
    float nb = (float)(n * 4);
    float4* qr = (float4*)(out + (size_t)n * 16);
    float4* qc = (float4*)(out + Tot + (size_t)n * 16);
#pragma unroll
    for (int i = 0; i < 4; ++i) {
        float ni = nb + (float)i;
        qr[i] = make_float4(ni, ni, ni, ni);
        qc[i] = make_float4(nb, nb + 1.0f, nb + 2.0f, nb + 3.0f);
    }
}

extern "C" void kernel_launch(void* const* d_in, const int* in_sizes, int n_in,
                              void* d_out, int out_size, void* d_ws, size_t ws_size,
                              hipStream_t stream) {
    const float* maps = (const float*)d_in[0];
    const int* ei = (const int*)d_in[1];

    int twoE = in_sizes[0] / 16;            // 1,600,000
    int E = twoE / 2;                       // 800,000
    size_t Tot = (size_t)out_size / 3;      // 26,400,000 elements per section
    int N = (int)(Tot / 16) - twoE;         // 50,000

    float* out = (float*)d_out;
    float* out_vals = out + 2 * Tot;

    // Scratch carved from the tail of d_out (inside the tri_ji VALS region —
    // k_fused1 writes only rows/cols sections, so no conflict; consumed by
    // k_gather_diag BEFORE k_edge_vals overwrites the vals tail):
    //   bucket: DEG_CAP*N ints (19.2MB, node-major) at the very end
    //   cnt:    N*16 ints (3.2MB, 64B-strided counters)
    int* bucket = (int*)(out + ((size_t)out_size - (size_t)DEG_CAP * N));
    int* cnt    = (int*)(out + ((size_t)out_size - (size_t)DEG_CAP * N - (size_t)N * 16));
    // R table: N*16 floats in the diag-rows region [0, N*16) — written by
    // k_gather_diag, read by k_edge_vals, overwritten last by k_nodeB.
    float* Rtab = out;

    hipMemsetAsync(cnt, 0, (size_t)N * 16 * sizeof(int), stream);

    int bs = 256;
    k_fused1<<<(twoE + bs - 1) / bs, bs, 0, stream>>>(ei, cnt, bucket, out, Tot, N, E);
    k_gather_diag<<<((size_t)N * 32 + bs - 1) / bs, bs, 0, stream>>>(maps, cnt, bucket, Rtab, out_vals, N);
    k_edge_vals<<<(E + bs - 1) / bs, bs, 0, stream>>>(maps, ei, Rtab, out_vals, N, E);
    k_nodeB<<<(N + bs - 1) / bs, bs, 0, stream>>>(out, Tot, N);
}